// Round 4
// baseline (276.810 us; speedup 1.0000x reference)
//
#include <hip/hip_runtime.h>

#define B_ 32
#define S_ 512
#define E_ 1024
#define P_ 256
#define HH 8
// rows = B*S = 16384

typedef __attribute__((ext_vector_type(8))) short bf16x8;
typedef __attribute__((ext_vector_type(8))) unsigned short us8;
typedef __attribute__((ext_vector_type(4))) unsigned short us4;
typedef __attribute__((ext_vector_type(16))) float f32x16;

static __device__ __forceinline__ unsigned short f2bf(float f) {
  union { float f; unsigned int u; } v;
  v.f = f;
  unsigned int r = (v.u + 0x7FFFu + ((v.u >> 16) & 1u)) >> 16;
  return (unsigned short)r;
}
static __device__ __forceinline__ float bf2f(unsigned short u) {
  union { unsigned int u; float f; } v;
  v.u = ((unsigned int)u) << 16;
  return v.f;
}

// ---------------- stage 0a: conv_w (O,I,K) -> wtT[o][k*256+i] bf16 ---------------
__global__ __launch_bounds__(256) void k_wtT(const float* __restrict__ cw,
                                             unsigned short* __restrict__ wtT) {
  int o = blockIdx.x, k = blockIdx.y, i = threadIdx.x;
  wtT[o * 768 + k * 256 + i] = f2bf(cw[o * 768 + i * 3 + k]);
}

// ---------------- stage 0b: pw [k][n] -> pwT[n][k] bf16 --------------------------
__global__ __launch_bounds__(256) void k_pwT(const float* __restrict__ pw,
                                             unsigned short* __restrict__ pwT) {
  __shared__ float T[32][33];
  int n0 = blockIdx.x * 32;   // 8 blocks
  int k0 = blockIdx.y * 32;   // 32 blocks
  int tx = threadIdx.x & 31, ty = threadIdx.x >> 5;
#pragma unroll
  for (int i = 0; i < 4; i++)
    T[ty + i * 8][tx] = pw[(k0 + ty + i * 8) * P_ + n0 + tx];
  __syncthreads();
#pragma unroll
  for (int i = 0; i < 4; i++)
    pwT[(size_t)(n0 + ty + i * 8) * E_ + k0 + tx] = f2bf(T[tx][ty + i * 8]);
}

// ---------------- stage 0c: attn_w [k][j] -> awT[j][k] bf16 ----------------------
__global__ __launch_bounds__(256) void k_awT(const float* __restrict__ aw,
                                             unsigned short* __restrict__ awT) {
  __shared__ float T[32][33];
  int j0 = blockIdx.x * 32;   // 128 blocks
  int k0 = blockIdx.y * 32;   // 8 blocks
  int tx = threadIdx.x & 31, ty = threadIdx.x >> 5;
#pragma unroll
  for (int i = 0; i < 4; i++)
    T[ty + i * 8][tx] = aw[(k0 + ty + i * 8) * 4096 + j0 + tx];
  __syncthreads();
#pragma unroll
  for (int i = 0; i < 4; i++)
    awT[(size_t)(j0 + ty + i * 8) * 256 + k0 + tx] = f2bf(T[tx][ty + i * 8]);
}

// ---------------- zero Z (16K) + wB (16K) + repA (8K) floats, contiguous ---------
__global__ __launch_bounds__(256) void k_zero(float* __restrict__ p) {
  p[blockIdx.x * 256 + threadIdx.x] = 0.f;
}

// ---------------- stage 1: proj16 = bf16(x @ pw + pb)  (16384x1024x256) ----------
__global__ __launch_bounds__(256) void k_proj_mfma(const float* __restrict__ x,
                                                   const unsigned short* __restrict__ pwT,
                                                   const float* __restrict__ pb,
                                                   unsigned short* __restrict__ proj16) {
  __shared__ unsigned short As[16 * 64 * 8];  // (kk2*64 + row)*8, 16 KiB
  const int m0 = blockIdx.x * 64;
  const int t = threadIdx.x;
  const int w = t >> 6, lane = t & 63, ln31 = lane & 31, kh = lane >> 5;
  const int c0 = w * 64;

  f32x16 acc00, acc01, acc10, acc11;
#pragma unroll
  for (int r = 0; r < 16; r++) { acc00[r] = 0.f; acc01[r] = 0.f; acc10[r] = 0.f; acc11[r] = 0.f; }

  const unsigned short* bp0 = pwT + (size_t)(c0 + ln31) * E_ + kh * 8;
  const unsigned short* bp1 = bp0 + (size_t)32 * E_;

  for (int kc = 0; kc < E_; kc += 128) {
#pragma unroll
    for (int i = 0; i < 8; i++) {
      int c = t + i * 256;
      int row = c >> 5, pos = c & 31;
      float4 v = *(const float4*)(x + (size_t)(m0 + row) * E_ + kc + pos * 4);
      us4 h;
      h[0] = f2bf(v.x); h[1] = f2bf(v.y); h[2] = f2bf(v.z); h[3] = f2bf(v.w);
      *(us4*)&As[((pos >> 1) * 64 + row) * 8 + (pos & 1) * 4] = h;
    }
    __syncthreads();
#pragma unroll
    for (int kk = 0; kk < 8; kk++) {
      bf16x8 a0 = *(const bf16x8*)&As[((2 * kk + kh) * 64 + ln31) * 8];
      bf16x8 a1 = *(const bf16x8*)&As[((2 * kk + kh) * 64 + 32 + ln31) * 8];
      bf16x8 b0 = *(const bf16x8*)(bp0 + kc + kk * 16);
      bf16x8 b1 = *(const bf16x8*)(bp1 + kc + kk * 16);
      acc00 = __builtin_amdgcn_mfma_f32_32x32x16_bf16(a0, b0, acc00, 0, 0, 0);
      acc01 = __builtin_amdgcn_mfma_f32_32x32x16_bf16(a0, b1, acc01, 0, 0, 0);
      acc10 = __builtin_amdgcn_mfma_f32_32x32x16_bf16(a1, b0, acc10, 0, 0, 0);
      acc11 = __builtin_amdgcn_mfma_f32_32x32x16_bf16(a1, b1, acc11, 0, 0, 0);
    }
    __syncthreads();
  }
  float pb0 = pb[c0 + ln31], pb1 = pb[c0 + 32 + ln31];
#pragma unroll
  for (int r = 0; r < 16; r++) {
    int rl = (r & 3) + 8 * (r >> 2) + 4 * kh;
    size_t g0 = (size_t)(m0 + rl) * P_;
    size_t g1 = (size_t)(m0 + 32 + rl) * P_;
    proj16[g0 + c0 + ln31]      = f2bf(acc00[r] + pb0);
    proj16[g0 + c0 + 32 + ln31] = f2bf(acc01[r] + pb1);
    proj16[g1 + c0 + ln31]      = f2bf(acc10[r] + pb0);
    proj16[g1 + c0 + 32 + ln31] = f2bf(acc11[r] + pb1);
  }
}

// ---------------- stage 2: conv-as-3-shift-GEMM -> rep16 (16384x768x256) ---------
__global__ __launch_bounds__(256) void k_conv_mfma(const unsigned short* __restrict__ proj16,
                                                   const unsigned short* __restrict__ wtT,
                                                   const float* __restrict__ cb,
                                                   const int* __restrict__ seq,
                                                   unsigned short* __restrict__ rep16) {
  __shared__ unsigned short As[32 * 66 * 8];  // (kk2*66 + row)*8, 33 KiB
  const int m0 = blockIdx.x * 64;
  const int bb = m0 >> 9, s0 = m0 & 511;
  const int t = threadIdx.x;
  const int w = t >> 6, lane = t & 63, ln31 = lane & 31, kh = lane >> 5;
  const int c0 = w * 64;

#pragma unroll
  for (int i = 0; i < 9; i++) {
    int c = t + i * 256;
    if (c < 2112) {
      int row = c >> 5, kk2 = c & 31;
      us8 v = {0, 0, 0, 0, 0, 0, 0, 0};
      if (s0 + row <= 511)
        v = *(const us8*)(proj16 + (size_t)(bb * S_ + s0 + row) * P_ + kk2 * 8);
      *(us8*)&As[(kk2 * 66 + row) * 8] = v;
    }
  }
  __syncthreads();

  f32x16 acc00, acc01, acc10, acc11;
#pragma unroll
  for (int r = 0; r < 16; r++) { acc00[r] = 0.f; acc01[r] = 0.f; acc10[r] = 0.f; acc11[r] = 0.f; }

  const unsigned short* bbase0 = wtT + (size_t)(c0 + ln31) * 768 + kh * 8;
  const unsigned short* bbase1 = bbase0 + (size_t)32 * 768;

#pragma unroll
  for (int k = 0; k < 3; k++) {
#pragma unroll
    for (int kk = 0; kk < 16; kk++) {
      bf16x8 a0 = *(const bf16x8*)&As[((2 * kk + kh) * 66 + k + ln31) * 8];
      bf16x8 a1 = *(const bf16x8*)&As[((2 * kk + kh) * 66 + k + 32 + ln31) * 8];
      bf16x8 b0 = *(const bf16x8*)(bbase0 + k * 256 + kk * 16);
      bf16x8 b1 = *(const bf16x8*)(bbase1 + k * 256 + kk * 16);
      acc00 = __builtin_amdgcn_mfma_f32_32x32x16_bf16(a0, b0, acc00, 0, 0, 0);
      acc01 = __builtin_amdgcn_mfma_f32_32x32x16_bf16(a0, b1, acc01, 0, 0, 0);
      acc10 = __builtin_amdgcn_mfma_f32_32x32x16_bf16(a1, b0, acc10, 0, 0, 0);
      acc11 = __builtin_amdgcn_mfma_f32_32x32x16_bf16(a1, b1, acc11, 0, 0, 0);
    }
  }

  int l = seq[bb];
  float cb0 = cb[c0 + ln31], cb1 = cb[c0 + 32 + ln31];
#pragma unroll
  for (int r = 0; r < 16; r++) {
    int rl = (r & 3) + 8 * (r >> 2) + 4 * kh;
    int s_a = s0 + rl, s_b = s0 + 32 + rl;
    float ma = (s_a >= 1 && s_a <= 509 && s_a < l - 1) ? 1.f : 0.f;
    float mb = (s_b >= 1 && s_b <= 509 && s_b < l - 1) ? 1.f : 0.f;
    size_t g0 = (size_t)(m0 + rl) * P_;
    size_t g1 = (size_t)(m0 + 32 + rl) * P_;
    rep16[g0 + c0 + ln31]      = f2bf(fmaxf(acc00[r] + cb0, 0.f) * ma);
    rep16[g0 + c0 + 32 + ln31] = f2bf(fmaxf(acc01[r] + cb1, 0.f) * ma);
    rep16[g1 + c0 + ln31]      = f2bf(fmaxf(acc10[r] + cb0, 0.f) * mb);
    rep16[g1 + c0 + 32 + ln31] = f2bf(fmaxf(acc11[r] + cb1, 0.f) * mb);
  }
}

// ---------------- stage 3: MFMA logits + exp + h-fold + Z-fold -> E16 bf16 -------
// block: 64 rows x 256 q. 4 waves, each 64 rows x 64 q (2x2 tiles, 4 MFMA chains).
// Epilogue: butterfly-reduce over 32 q-lanes -> atomicAdd partial row-sums to Z.
__global__ __launch_bounds__(256) void k_attn_mfma(const unsigned short* __restrict__ rep16,
                                                   const unsigned short* __restrict__ awT,
                                                   const float* __restrict__ ab,
                                                   unsigned short* __restrict__ E16,
                                                   float* __restrict__ Z) {
  __shared__ unsigned short As[64][264];
  const int m0 = blockIdx.x * 64;
  const int q0 = blockIdx.y * 256;
  const int t = threadIdx.x;
  const int w = t >> 6;
  const int lane = t & 63;
  const int ln31 = lane & 31;
  const int kh = lane >> 5;
  const int khalf = kh * 8;

  // stage A: 64 rows x 256 k (bf16) = 32 KB
#pragma unroll
  for (int i = 0; i < 8; i++) {
    int flat = i * 256 + t;
    int r = flat >> 5;
    int g = (flat & 31) * 8;
    us8 v = *(const us8*)(rep16 + (size_t)(m0 + r) * 256 + g);
    *(us8*)&As[r][g] = v;
  }
  __syncthreads();

  const int qb = q0 + w * 64;
  const int qc0 = qb + ln31;
  const int qc1 = qb + 32 + ln31;

  float ef00[16], ef01[16], ef10[16], ef11[16];
#pragma unroll
  for (int r = 0; r < 16; r++) { ef00[r] = 0.f; ef01[r] = 0.f; ef10[r] = 0.f; ef11[r] = 0.f; }

  for (int h = 0; h < HH; h++) {
    const unsigned short* b0p = awT + (size_t)(h * 512 + qc0) * 256 + khalf;
    const unsigned short* b1p = awT + (size_t)(h * 512 + qc1) * 256 + khalf;
    f32x16 acc00, acc01, acc10, acc11;
#pragma unroll
    for (int r = 0; r < 16; r++) { acc00[r] = 0.f; acc01[r] = 0.f; acc10[r] = 0.f; acc11[r] = 0.f; }

#pragma unroll
    for (int kc = 0; kc < 256; kc += 16) {
      bf16x8 a0 = *(const bf16x8*)&As[ln31][kc + khalf];
      bf16x8 a1 = *(const bf16x8*)&As[32 + ln31][kc + khalf];
      bf16x8 b0 = *(const bf16x8*)(b0p + kc);
      bf16x8 b1 = *(const bf16x8*)(b1p + kc);
      acc00 = __builtin_amdgcn_mfma_f32_32x32x16_bf16(a0, b0, acc00, 0, 0, 0);
      acc01 = __builtin_amdgcn_mfma_f32_32x32x16_bf16(a0, b1, acc01, 0, 0, 0);
      acc10 = __builtin_amdgcn_mfma_f32_32x32x16_bf16(a1, b0, acc10, 0, 0, 0);
      acc11 = __builtin_amdgcn_mfma_f32_32x32x16_bf16(a1, b1, acc11, 0, 0, 0);
    }
    float bias0 = ab[h * 512 + qc0];
    float bias1 = ab[h * 512 + qc1];
#pragma unroll
    for (int r = 0; r < 16; r++) {
      ef00[r] += __expf(acc00[r] + bias0);
      ef01[r] += __expf(acc01[r] + bias1);
      ef10[r] += __expf(acc10[r] + bias0);
      ef11[r] += __expf(acc11[r] + bias1);
    }
  }

  // store E16 (bf16)
#pragma unroll
  for (int r = 0; r < 16; r++) {
    int rl = (r & 3) + 8 * (r >> 2) + 4 * kh;
    size_t row0 = (size_t)(m0 + rl) * 512;
    size_t row1 = (size_t)(m0 + 32 + rl) * 512;
    E16[row0 + qc0] = f2bf(ef00[r]);
    E16[row0 + qc1] = f2bf(ef01[r]);
    E16[row1 + qc0] = f2bf(ef10[r]);
    E16[row1 + qc1] = f2bf(ef11[r]);
  }

  // Z partial row-sums: reduce over 32 q-lanes, atomicAdd per row
#pragma unroll
  for (int r = 0; r < 16; r++) {
    float z0 = ef00[r] + ef01[r];
    float z1 = ef10[r] + ef11[r];
#pragma unroll
    for (int st = 16; st >= 1; st >>= 1) {
      z0 += __shfl_xor(z0, st, 64);
      z1 += __shfl_xor(z1, st, 64);
    }
    if (ln31 == 0) {
      int rl = (r & 3) + 8 * (r >> 2) + 4 * kh;
      atomicAdd(&Z[m0 + rl], z0);
      atomicAdd(&Z[m0 + 32 + rl], z1);
    }
  }
}

// ---------------- stage 4: w[b,q] = (1/H) sum_s E16[b,s,q]/Z[b,s] ----------------
__global__ __launch_bounds__(512) void k_w(const unsigned short* __restrict__ E16,
                                           const float* __restrict__ Z,
                                           float* __restrict__ wB) {
  __shared__ float rZ[64];
  int b = blockIdx.x, c = blockIdx.y, t = threadIdx.x;
  int s0 = c * 64;
  if (t < 64) rZ[t] = 1.0f / Z[b * 512 + s0 + t];
  __syncthreads();
  float acc = 0.f;
#pragma unroll 8
  for (int s = 0; s < 64; s++)
    acc += bf2f(E16[(size_t)(b * 512 + s0 + s) * 512 + t]) * rZ[s];
  atomicAdd(&wB[b * 512 + t], acc * (1.0f / HH));
}

// ---------------- stage 5a: repA[b,p] = sum_q w[b,q] * rep16[b,q,p] --------------
__global__ __launch_bounds__(256) void k_final_a(const unsigned short* __restrict__ rep16,
                                                 const float* __restrict__ wB,
                                                 float* __restrict__ repA) {
  __shared__ float wS[64];
  int b = blockIdx.x, qc = blockIdx.y, t = threadIdx.x;
  if (t < 64) wS[t] = wB[b * 512 + qc * 64 + t];
  __syncthreads();
  float acc = 0.f;
  const unsigned short* base = rep16 + (size_t)(b * 512 + qc * 64) * 256 + t;
#pragma unroll 8
  for (int q = 0; q < 64; q++) acc += wS[q] * bf2f(base[(size_t)q * 256]);
  atomicAdd(&repA[b * 256 + t], acc);
}

// ---------------- stage 5b: heads -> probs + argmax ------------------------------
__global__ __launch_bounds__(128) void k_final_b(const float* __restrict__ repA,
                                                 const float* __restrict__ c1w,
                                                 const float* __restrict__ c1b,
                                                 const float* __restrict__ c2w,
                                                 const float* __restrict__ c2b,
                                                 float* __restrict__ out) {
  __shared__ float hS[128];
  __shared__ float clsS[2];
  int b = blockIdx.x, t = threadIdx.x;
  float acc = c1b[t];
  for (int p = 0; p < 256; p++) acc += repA[b * 256 + p] * c1w[p * 128 + t];
  hS[t] = acc > 0.f ? acc : 0.01f * acc;
  __syncthreads();
  if (t < 2) {
    float a2 = c2b[t];
    for (int j = 0; j < 128; j++) a2 += hS[j] * c2w[j * 2 + t];
    clsS[t] = a2;
  }
  __syncthreads();
  if (t == 0) {
    float c0 = clsS[0], c1 = clsS[1];
    float m = fmaxf(c0, c1);
    float e0 = __expf(c0 - m), e1 = __expf(c1 - m);
    float inv = 1.0f / (e0 + e1);
    float p0 = e0 * inv, p1 = e1 * inv;
    out[b * 2 + 0] = p0;
    out[b * 2 + 1] = p1;
    out[B_ * 2 + b] = (p1 > p0) ? 1.0f : 0.0f;
  }
}

extern "C" void kernel_launch(void* const* d_in, const int* in_sizes, int n_in,
                              void* d_out, int out_size, void* d_ws, size_t ws_size,
                              hipStream_t stream) {
  const float* x   = (const float*)d_in[0];
  const int*   seq = (const int*)d_in[1];
  const float* pw  = (const float*)d_in[2];
  const float* pb  = (const float*)d_in[3];
  const float* cw  = (const float*)d_in[4];
  const float* cb  = (const float*)d_in[5];
  const float* aw  = (const float*)d_in[6];
  const float* ab  = (const float*)d_in[7];
  const float* c1w = (const float*)d_in[8];
  const float* c1b = (const float*)d_in[9];
  const float* c2w = (const float*)d_in[10];
  const float* c2b = (const float*)d_in[11];
  float* out = (float*)d_out;

  char* ws = (char*)d_ws;
  // proj16 (8 MiB) overlaps E16 (16 MiB): proj16 dies (k_conv) before E16 written
  unsigned short* proj16 = (unsigned short*)(ws);
  unsigned short* E16    = (unsigned short*)(ws);                     // 16 MiB @ 0
  unsigned short* rep16  = (unsigned short*)(ws + (size_t)16777216);  // 8 MiB
  unsigned short* pwT    = (unsigned short*)(ws + (size_t)25165824);  // 512 KiB
  unsigned short* wtT    = (unsigned short*)(ws + (size_t)25690112);  // 384 KiB
  unsigned short* awT    = (unsigned short*)(ws + (size_t)26083328);  // 2 MiB
  float*          Z      = (float*)(ws + (size_t)28180480);           // 64 KiB
  float*          wB     = (float*)(ws + (size_t)28246016);           // 64 KiB
  float*          repA   = (float*)(ws + (size_t)28311552);           // 32 KiB

  k_zero<<<160, 256, 0, stream>>>(Z);  // Z + wB + repA contiguous (40960 floats)
  k_wtT<<<dim3(256, 3), 256, 0, stream>>>(cw, wtT);
  k_pwT<<<dim3(8, 32), 256, 0, stream>>>(pw, pwT);
  k_awT<<<dim3(128, 8), 256, 0, stream>>>(aw, awT);
  k_proj_mfma<<<256, 256, 0, stream>>>(x, pwT, pb, proj16);
  k_conv_mfma<<<256, 256, 0, stream>>>(proj16, wtT, cb, seq, rep16);
  k_attn_mfma<<<dim3(256, 2), 256, 0, stream>>>(rep16, awT, ab, E16, Z);
  k_w<<<dim3(32, 8), 512, 0, stream>>>(E16, Z, wB);
  k_final_a<<<dim3(32, 8), 256, 0, stream>>>(rep16, wB, repA);
  k_final_b<<<32, 128, 0, stream>>>(repA, c1w, c1b, c2w, c2b, out);
}